// Round 1
// baseline (359.364 us; speedup 1.0000x reference)
//
#include <hip/hip_runtime.h>

#define D_FEAT 32

// ---------------- shared small kernels ----------------

__global__ void norm_kernel(const int* __restrict__ deg, float* __restrict__ norm, int n_nodes) {
    int i = blockIdx.x * blockDim.x + threadIdx.x;
    if (i < n_nodes) {
        int d = deg[i];
        norm[i] = d > 0 ? rsqrtf((float)d) : 0.0f;
    }
}

// ---------------- CSR-gather path ----------------

// One pass over edges: out-degree (for norm) and in-degree (for CSR offsets).
__global__ void deg2_kernel(const int* __restrict__ src, const int* __restrict__ dst,
                            int* __restrict__ deg_out, int* __restrict__ deg_in, int n_edges) {
    int e = blockIdx.x * blockDim.x + threadIdx.x;
    if (e < n_edges) {
        atomicAdd(&deg_out[src[e]], 1);
        atomicAdd(&deg_in[dst[e]], 1);
    }
}

// Per-block sums of deg_in -> bsum[block]
__global__ void scan_block_sums(const int* __restrict__ deg_in, int* __restrict__ bsum, int n) {
    __shared__ int sdata[256];
    int i = blockIdx.x * 256 + threadIdx.x;
    sdata[threadIdx.x] = (i < n) ? deg_in[i] : 0;
    __syncthreads();
    for (int s = 128; s > 0; s >>= 1) {
        if ((int)threadIdx.x < s) sdata[threadIdx.x] += sdata[threadIdx.x + s];
        __syncthreads();
    }
    if (threadIdx.x == 0) bsum[blockIdx.x] = sdata[0];
}

// Single-block exclusive scan of bsum (in place), chunked with carry.
__global__ void scan_partials(int* __restrict__ data, int n) {
    __shared__ int buf[1024];
    __shared__ int carry_s;
    if (threadIdx.x == 0) carry_s = 0;
    __syncthreads();
    for (int base = 0; base < n; base += 1024) {
        int idx = base + (int)threadIdx.x;
        int x = (idx < n) ? data[idx] : 0;
        buf[threadIdx.x] = x;
        __syncthreads();
        int sum = x;
        for (int off = 1; off < 1024; off <<= 1) {
            int t = ((int)threadIdx.x >= off) ? buf[threadIdx.x - off] : 0;
            __syncthreads();
            sum += t;
            buf[threadIdx.x] = sum;
            __syncthreads();
        }
        int carry = carry_s;
        if (idx < n) data[idx] = carry + sum - x;  // exclusive
        __syncthreads();
        if (threadIdx.x == 1023) carry_s = carry + buf[1023];
        __syncthreads();
    }
}

// Intra-block exclusive scan + block offset -> row_start; last thread appends total.
__global__ void scan_final(const int* __restrict__ deg_in, const int* __restrict__ bsum,
                           int* __restrict__ row_start, int n) {
    __shared__ int buf[256];
    int i = blockIdx.x * 256 + threadIdx.x;
    int x = (i < n) ? deg_in[i] : 0;
    buf[threadIdx.x] = x;
    __syncthreads();
    int sum = x;
    for (int off = 1; off < 256; off <<= 1) {
        int t = ((int)threadIdx.x >= off) ? buf[threadIdx.x - off] : 0;
        __syncthreads();
        sum += t;
        buf[threadIdx.x] = sum;
        __syncthreads();
    }
    int excl = bsum[blockIdx.x] + sum - x;
    if (i < n) row_start[i] = excl;
    if (i == n - 1) row_start[n] = excl + x;
}

// Bucket edges by destination.
__global__ void fill_csr(const int* __restrict__ src, const int* __restrict__ dst,
                         const int* __restrict__ row_start, int* __restrict__ cursor,
                         int* __restrict__ edge_src, int n_edges) {
    int e = blockIdx.x * blockDim.x + threadIdx.x;
    if (e < n_edges) {
        int d = dst[e];
        int pos = row_start[d] + atomicAdd(&cursor[d], 1);
        edge_src[pos] = src[e];
    }
}

// 32 lanes per destination node: lane d owns feature dim d. No atomics; out written once.
__global__ __launch_bounds__(256) void gather_kernel(const float* __restrict__ feat,
                                                     const int* __restrict__ edge_src,
                                                     const int* __restrict__ row_start,
                                                     const float* __restrict__ norm,
                                                     float* __restrict__ out, int n_nodes) {
    int t = blockIdx.x * blockDim.x + threadIdx.x;
    int node = t >> 5;
    int d = t & 31;
    if (node >= n_nodes) return;
    int beg = row_start[node];
    int end = row_start[node + 1];
    float acc = 0.0f;
    int j = beg;
    // 2-wide unroll for memory-level parallelism
    for (; j + 1 < end; j += 2) {
        int s0 = edge_src[j];
        int s1 = edge_src[j + 1];
        float a0 = feat[s0 * D_FEAT + d] * norm[s0];
        float a1 = feat[s1 * D_FEAT + d] * norm[s1];
        acc += a0 + a1;
    }
    if (j < end) {
        int s = edge_src[j];
        acc += feat[s * D_FEAT + d] * norm[s];
    }
    out[node * D_FEAT + d] = acc * norm[node];
}

// ---------------- fallback atomic-scatter path (old kernel) ----------------

__global__ void deg_kernel(const int* __restrict__ src, int* __restrict__ deg, int n_edges) {
    int e = blockIdx.x * blockDim.x + threadIdx.x;
    if (e < n_edges) atomicAdd(&deg[src[e]], 1);
}

__global__ void scatter_kernel(const float* __restrict__ feat,
                               const int* __restrict__ src,
                               const int* __restrict__ dst,
                               const float* __restrict__ norm,
                               float* __restrict__ out, int n_edges) {
    int t = blockIdx.x * blockDim.x + threadIdx.x;
    int e = t >> 5;
    int d = t & 31;
    if (e < n_edges) {
        int s  = src[e];
        int dd = dst[e];
        float v = feat[s * D_FEAT + d] * norm[s];
        atomicAdd(&out[dd * D_FEAT + d], v);
    }
}

__global__ void post_scale_kernel(float4* __restrict__ out4,
                                  const float* __restrict__ norm, int n4) {
    int t = blockIdx.x * blockDim.x + threadIdx.x;
    if (t < n4) {
        float nv = norm[t >> 3];
        float4 v = out4[t];
        v.x *= nv; v.y *= nv; v.z *= nv; v.w *= nv;
        out4[t] = v;
    }
}

// ---------------- launch ----------------

extern "C" void kernel_launch(void* const* d_in, const int* in_sizes, int n_in,
                              void* d_out, int out_size, void* d_ws, size_t ws_size,
                              hipStream_t stream) {
    const float* feat = (const float*)d_in[0];
    const int*   src  = (const int*)d_in[1];
    const int*   dst  = (const int*)d_in[2];
    float* out = (float*)d_out;

    const int n_nodes = in_sizes[0] / D_FEAT;
    const int n_edges = in_sizes[1];
    const int B = 256;
    const int nblk = (n_nodes + B - 1) / B;

    // Workspace layout for CSR path
    auto align256 = [](size_t x) { return (x + 255) & ~(size_t)255; };
    size_t counts_bytes = (size_t)3 * n_nodes * sizeof(int);   // deg_out | deg_in | cursor (contiguous: one memset)
    size_t off = align256(counts_bytes);
    size_t norm_off = off;  off = align256(off + (size_t)n_nodes * sizeof(float));
    size_t rs_off   = off;  off = align256(off + (size_t)(n_nodes + 1) * sizeof(int));
    size_t bsum_off = off;  off = align256(off + (size_t)nblk * sizeof(int));
    size_t esrc_off = off;  off = align256(off + (size_t)n_edges * sizeof(int));
    size_t needed = off;

    if (ws_size >= needed) {
        int*   deg_out_p = (int*)d_ws;
        int*   deg_in_p  = deg_out_p + n_nodes;
        int*   cursor_p  = deg_out_p + 2 * (size_t)n_nodes;
        float* norm_p    = (float*)((char*)d_ws + norm_off);
        int*   row_start = (int*)((char*)d_ws + rs_off);
        int*   bsum_p    = (int*)((char*)d_ws + bsum_off);
        int*   edge_src  = (int*)((char*)d_ws + esrc_off);

        hipMemsetAsync(deg_out_p, 0, counts_bytes, stream);

        deg2_kernel<<<(n_edges + B - 1) / B, B, 0, stream>>>(src, dst, deg_out_p, deg_in_p, n_edges);
        norm_kernel<<<nblk, B, 0, stream>>>(deg_out_p, norm_p, n_nodes);

        scan_block_sums<<<nblk, B, 0, stream>>>(deg_in_p, bsum_p, n_nodes);
        scan_partials<<<1, 1024, 0, stream>>>(bsum_p, nblk);
        scan_final<<<nblk, B, 0, stream>>>(deg_in_p, bsum_p, row_start, n_nodes);

        fill_csr<<<(n_edges + B - 1) / B, B, 0, stream>>>(src, dst, row_start, cursor_p, edge_src, n_edges);

        long long total = (long long)n_nodes * 32;
        int grid = (int)((total + B - 1) / B);
        gather_kernel<<<grid, B, 0, stream>>>(feat, edge_src, row_start, norm_p, out, n_nodes);
    } else {
        // fallback: old atomic-scatter path (deg | norm in ws)
        int*   deg  = (int*)d_ws;
        float* norm = (float*)((char*)d_ws + (((size_t)n_nodes * sizeof(int) + 255) & ~(size_t)255));

        hipMemsetAsync(deg, 0, (size_t)n_nodes * sizeof(int), stream);
        hipMemsetAsync(d_out, 0, (size_t)out_size * sizeof(float), stream);

        deg_kernel<<<(n_edges + B - 1) / B, B, 0, stream>>>(src, deg, n_edges);
        norm_kernel<<<nblk, B, 0, stream>>>(deg, norm, n_nodes);

        long long total = (long long)n_edges * 32;
        int grid = (int)((total + B - 1) / B);
        scatter_kernel<<<grid, B, 0, stream>>>(feat, src, dst, norm, out, n_edges);

        int n4 = out_size / 4;
        post_scale_kernel<<<(n4 + B - 1) / B, B, 0, stream>>>((float4*)out, norm, n4);
    }
}